// Round 9
// baseline (349.529 us; speedup 1.0000x reference)
//
#include <hip/hip_runtime.h>

typedef _Float16 f16x8 __attribute__((ext_vector_type(8)));
typedef _Float16 f16x4 __attribute__((ext_vector_type(4)));
typedef float f32x4 __attribute__((ext_vector_type(4)));

#define D_IN 768
#define D_H  256
#define SEQ  2048

// ---------------- K0: W1 [768][256] f32 -> W1T [256][768] f16 (transposed) ---
__global__ __launch_bounds__(256) void k0_w1t(const float* __restrict__ W1,
                                              _Float16* __restrict__ W1T) {
  __shared__ float tl[64][65];
  const int kb = blockIdx.x, nb = blockIdx.y, t = threadIdx.x;
#pragma unroll
  for (int rep = 0; rep < 16; ++rep) {
    const int row = rep * 4 + (t >> 6), col = t & 63;
    tl[row][col] = W1[(size_t)(kb * 64 + row) * D_H + nb * 64 + col];
  }
  __syncthreads();
#pragma unroll
  for (int rep = 0; rep < 16; ++rep) {
    const int n = rep * 4 + (t >> 6), k = t & 63;
    W1T[(size_t)(nb * 64 + n) * D_IN + kb * 64 + k] = (_Float16)tl[k][n];
  }
}

// ---------------- KF: fused logits + local softmax + local pooling -----------
// 4096 blocks (32 rows) x 256 threads, 51KB LDS -> 3 blocks/CU.
// PAGE-SEQUENTIAL staging: the block's X-tile is contiguous 96KB; a burst of
// 24 float4/thread reads each DRAM page once, start to finish.
// K-loop: 24 steps of K=32 (FULL 768 — R8 bug was 12 steps = half of K).
__global__ __launch_bounds__(256, 3) void kf_fused(const float* __restrict__ X,
    const _Float16* __restrict__ W1T, const float* __restrict__ b1,
    const float* __restrict__ C, _Float16* __restrict__ Ppart,
    float* __restrict__ stats) {
  __shared__ _Float16 Xl[32][776];   // 48.5KB, +8 pad -> bank shift 4/row
  __shared__ float red2[4][32][4];   //  2KB per-wave logit partials
  __shared__ float red[32][4];       //  512B
  const int t = threadIdx.x;
  const int bid = blockIdx.x;
  const size_t M0 = (size_t)bid * 32;

  // ---- phase A: contiguous 96KB burst = 24 float4/thread (6144 chunks) ----
  const float* Xbase = X + M0 * D_IN;       // contiguous 24576 floats
  float4 L0[12], L1[12];
#pragma unroll
  for (int i = 0; i < 12; ++i)
    L0[i] = *(const float4*)(Xbase + (size_t)(i * 256 + t) * 4);
#pragma unroll
  for (int i = 0; i < 12; ++i)
    L1[i] = *(const float4*)(Xbase + (size_t)((12 + i) * 256 + t) * 4);
#pragma unroll
  for (int i = 0; i < 12; ++i) {
    const int f = i * 256 + t;              // float4-chunk index 0..3071
    const int row = f / 192;                // rows 0..15
    const int jj = f - row * 192;
    f16x4 h;
    h[0] = (_Float16)L0[i].x; h[1] = (_Float16)L0[i].y;
    h[2] = (_Float16)L0[i].z; h[3] = (_Float16)L0[i].w;
    *(f16x4*)&Xl[row][jj * 4] = h;
  }
#pragma unroll
  for (int i = 0; i < 12; ++i) {
    const int f = (12 + i) * 256 + t;       // chunk index 3072..6143
    const int row = f / 192;                // rows 16..31
    const int jj = f - row * 192;
    f16x4 h;
    h[0] = (_Float16)L1[i].x; h[1] = (_Float16)L1[i].y;
    h[2] = (_Float16)L1[i].z; h[3] = (_Float16)L1[i].w;
    *(f16x4*)&Xl[row][jj * 4] = h;
  }
  __syncthreads();   // the ONLY pre-epilogue barrier

  // ---- phase B: K-loop (24 x K=32, full 768), barrier-free; B from L2 ----
  const int l = t & 63, wn = t >> 6;        // 4 waves x 64 cols
  const int l15 = l & 15, kg = l >> 4;

  f32x4 acc[2][4];
#pragma unroll
  for (int i = 0; i < 2; ++i)
#pragma unroll
    for (int g = 0; g < 4; ++g) acc[i][g] = f32x4{0.f, 0.f, 0.f, 0.f};

#pragma unroll
  for (int kt = 0; kt < 24; ++kt) {
    const f16x8 af0 = *(const f16x8*)&Xl[l15][kt * 32 + kg * 8];
    const f16x8 af1 = *(const f16x8*)&Xl[16 + l15][kt * 32 + kg * 8];
#pragma unroll
    for (int g = 0; g < 4; ++g) {
      const int col = wn * 64 + g * 16 + l15;
      const f16x8 bf = *(const f16x8*)(W1T + (size_t)col * D_IN + kt * 32 + kg * 8);
      acc[0][g] = __builtin_amdgcn_mfma_f32_16x16x32_f16(af0, bf, acc[0][g], 0, 0, 0);
      acc[1][g] = __builtin_amdgcn_mfma_f32_16x16x32_f16(af1, bf, acc[1][g], 0, 0, 0);
    }
  }

  // ---- epilogue 1: z -> tanh -> project onto 4 context vectors ----
  float part[2][4][4];
#pragma unroll
  for (int i = 0; i < 2; ++i)
#pragma unroll
    for (int r = 0; r < 4; ++r)
#pragma unroll
      for (int c = 0; c < 4; ++c) part[i][r][c] = 0.f;

#pragma unroll
  for (int g = 0; g < 4; ++g) {
    const int col = wn * 64 + g * 16 + l15;
    const float4 c4 = *(const float4*)(C + col * 4);
    const float bv = b1[col];
#pragma unroll
    for (int i = 0; i < 2; ++i)
#pragma unroll
      for (int r = 0; r < 4; ++r) {
        float z = acc[i][g][r] + bv;
        z = fminf(fmaxf(z, -15.f), 15.f);
        const float e = __expf(2.f * z);
        const float h = (e - 1.f) / (e + 1.f);   // tanh(z)
        part[i][r][0] += h * c4.x;
        part[i][r][1] += h * c4.y;
        part[i][r][2] += h * c4.z;
        part[i][r][3] += h * c4.w;
      }
  }
#pragma unroll
  for (int off = 1; off < 16; off <<= 1) {
#pragma unroll
    for (int i = 0; i < 2; ++i)
#pragma unroll
      for (int r = 0; r < 4; ++r)
#pragma unroll
        for (int c = 0; c < 4; ++c)
          part[i][r][c] += __shfl_xor(part[i][r][c], off, 64);
  }
  if (l15 == 0) {
#pragma unroll
    for (int i = 0; i < 2; ++i)
#pragma unroll
      for (int r = 0; r < 4; ++r)
#pragma unroll
        for (int c = 0; c < 4; ++c)
          red2[wn][i * 16 + kg * 4 + r][c] = part[i][r][c];
  }
  __syncthreads();

  // ---- epilogue 2: sum wave-partials; block-local softmax (wave-parallel) ----
  if (t < 128) {
    const int r = t >> 2, c = t & 3;
    red[r][c] = red2[0][r][c] + red2[1][r][c] + red2[2][r][c] + red2[3][r][c];
  }
  __syncthreads();
  {
    const int c = t >> 6, r = t & 63;   // 4 waves, one per context
    const float v = (r < 32) ? red[r][c] : -3.4e38f;
    float m = v;
#pragma unroll
    for (int off = 1; off < 64; off <<= 1) m = fmaxf(m, __shfl_xor(m, off, 64));
    const float e = (r < 32) ? __expf(v - m) : 0.f;
    if (r < 32) red[r][c] = e;
    float s = e;
#pragma unroll
    for (int off = 1; off < 64; off <<= 1) s += __shfl_xor(s, off, 64);
    if (r == 0) {
      stats[(size_t)bid * 8 + c * 2]     = m;
      stats[(size_t)bid * 8 + c * 2 + 1] = s;
    }
  }
  __syncthreads();

  // ---- epilogue 3: partial pooling from LDS (f16) ----
  {
    const int c = t >> 6;
    for (int g = (t & 63); g < 96; g += 64) {   // f16x8 granule within row
      float a8[8] = {0.f, 0.f, 0.f, 0.f, 0.f, 0.f, 0.f, 0.f};
#pragma unroll 8
      for (int r = 0; r < 32; ++r) {
        const float w = red[r][c];
        const f16x8 x8 = *(const f16x8*)&Xl[r][g * 8];
#pragma unroll
        for (int k = 0; k < 8; ++k) a8[k] += w * (float)x8[k];
      }
      f16x8 o;
#pragma unroll
      for (int k = 0; k < 8; ++k) o[k] = (_Float16)a8[k];
      *(f16x8*)&Ppart[(size_t)bid * 3072 + c * 768 + g * 8] = o;
    }
  }
}

// ---------------- KC: combine 64 block-partials per batch -> pooled ----------
__global__ __launch_bounds__(256) void kc_combine(const _Float16* __restrict__ Ppart,
    const float* __restrict__ stats, float* __restrict__ pooled) {
  const int b = blockIdx.x, t = threadIdx.x;
  __shared__ float sm[64][8];
  __shared__ float Mc[4], Dc[4], fw[64][4];
  sm[t >> 2][(t & 3) * 2]     = stats[((size_t)b * 64 + (t >> 2)) * 8 + (t & 3) * 2];
  sm[t >> 2][(t & 3) * 2 + 1] = stats[((size_t)b * 64 + (t >> 2)) * 8 + (t & 3) * 2 + 1];
  __syncthreads();
  if (t < 4) {
    float m = sm[0][t * 2];
#pragma unroll 8
    for (int blk = 1; blk < 64; ++blk) m = fmaxf(m, sm[blk][t * 2]);
    Mc[t] = m;
  }
  __syncthreads();
  {
    const int blk = t >> 2, c = t & 3;
    fw[blk][c] = __expf(sm[blk][c * 2] - Mc[c]);
  }
  __syncthreads();
  if (t < 4) {
    float s = 0.f;
#pragma unroll 8
    for (int blk = 0; blk < 64; ++blk) s += fw[blk][t] * sm[blk][t * 2 + 1];
    Dc[t] = 1.f / s;
  }
  __syncthreads();
#pragma unroll
  for (int c = 0; c < 4; ++c) {
#pragma unroll
    for (int rep = 0; rep < 3; ++rep) {
      const int d = rep * 256 + t;
      float acc = 0.f;
#pragma unroll 8
      for (int blk = 0; blk < 64; ++blk)
        acc += fw[blk][c] * (float)Ppart[((size_t)(b * 64 + blk)) * 3072 + c * 768 + d];
      pooled[(size_t)b * 3072 + c * 768 + d] = fmaxf(acc * Dc[c], 0.f);
    }
  }
}

// ---------------- K4: partial[kc][b][j] = pooled(k-slice) @ W2(k-slice) ------
__global__ __launch_bounds__(256) void k4_partial(const float* __restrict__ pooled,
                                                  const float* __restrict__ W2,
                                                  float* __restrict__ partial) {
  const int jc = blockIdx.x, kc = blockIdx.y, t = threadIdx.x;
  __shared__ float plds[64 * 192];
  __shared__ float sum2[64][64];
  for (int idx = t; idx < 64 * 192; idx += 256) {
    const int b = idx / 192, k = idx - b * 192;
    plds[idx] = pooled[(size_t)b * 3072 + kc * 192 + k];
  }
  __syncthreads();
  const int j = t & 63, kp = t >> 6;
  float acc[64];
#pragma unroll
  for (int b = 0; b < 64; ++b) acc[b] = 0.f;
  const float* W2p = W2 + (size_t)(kc * 192 + kp * 48) * D_IN + jc * 64 + j;
  const float* pb = plds + kp * 48;
  for (int ki = 0; ki < 48; ki += 4) {
    const float w0 = W2p[(size_t)(ki + 0) * D_IN];
    const float w1 = W2p[(size_t)(ki + 1) * D_IN];
    const float w2 = W2p[(size_t)(ki + 2) * D_IN];
    const float w3 = W2p[(size_t)(ki + 3) * D_IN];
#pragma unroll
    for (int b = 0; b < 64; ++b) {
      const float4 p4 = *(const float4*)(pb + b * 192 + ki);
      acc[b] += p4.x * w0 + p4.y * w1 + p4.z * w2 + p4.w * w3;
    }
  }
#pragma unroll
  for (int p = 0; p < 4; ++p) {
    if (kp == p) {
      if (p == 0) {
#pragma unroll
        for (int b = 0; b < 64; ++b) sum2[b][j] = acc[b];
      } else {
#pragma unroll
        for (int b = 0; b < 64; ++b) sum2[b][j] += acc[b];
      }
    }
    __syncthreads();
  }
  for (int idx = t; idx < 4096; idx += 256) {
    const int b = idx >> 6, jj = idx & 63;
    partial[(size_t)kc * 49152 + (size_t)b * D_IN + jc * 64 + jj] = sum2[b][jj];
  }
}

// ---------------- K5: out = sum(partials) + b2 -------------------------------
__global__ __launch_bounds__(256) void k5_final(const float* __restrict__ partial,
                                                const float* __restrict__ b2,
                                                float* __restrict__ out) {
  const int o = blockIdx.x * 256 + threadIdx.x;
  float v = b2[o % D_IN];
#pragma unroll
  for (int p = 0; p < 16; ++p) v += partial[(size_t)p * 49152 + o];
  out[o] = v;
}

extern "C" void kernel_launch(void* const* d_in, const int* in_sizes, int n_in,
                              void* d_out, int out_size, void* d_ws, size_t ws_size,
                              hipStream_t stream) {
  const float* X  = (const float*)d_in[0];
  const float* W1 = (const float*)d_in[1];
  const float* b1 = (const float*)d_in[2];
  const float* C  = (const float*)d_in[3];
  const float* W2 = (const float*)d_in[4];
  const float* b2 = (const float*)d_in[5];
  float* out = (float*)d_out;
  char* ws = (char*)d_ws;
  _Float16* W1T   = (_Float16*)ws;              //         0 ..   393,216
  float* pooled   = (float*)(ws + 393216);      //   393,216 .. 1,179,648
  float* stats    = (float*)(ws + 1179648);     // 1,179,648 .. 1,310,720
  _Float16* Ppart = (_Float16*)(ws + 1310720);  // 1,310,720 .. 26,476,544
  float* partial  = (float*)(ws + 1310720);     // aliases Ppart (used after KC)

  k0_w1t    <<<dim3(12, 4), 256, 0, stream>>>(W1, W1T);
  kf_fused  <<<4096,        256, 0, stream>>>(X, W1T, b1, C, Ppart, stats);
  kc_combine<<<64,          256, 0, stream>>>(Ppart, stats, pooled);
  k4_partial<<<dim3(12,16), 256, 0, stream>>>(pooled, W2, partial);
  k5_final  <<<192,         256, 0, stream>>>(partial, b2, out);
}